// Round 1
// baseline (344.419 us; speedup 1.0000x reference)
//
#include <hip/hip_runtime.h>

// db1 inverse wavelet transform (grouped transposed conv, k=2, stride=2).
// x: (B=16, C=128, H=128, W=128) fp32 -> out: (B=16, G=64, 256, 256) fp32.
// out[b,g,2h+i,2w+j] = x[b,2g,h,w]*f0[i][j] + x[b,2g+1,h,w]*f1[i][j]
//
// Memory-bound streaming op: 128 MiB read + 256 MiB write -> ~64 us at 6.3 TB/s.
// One thread per (b,g,h, w-pair): float2 loads, two float4 stores (coalesced).

__global__ __launch_bounds__(256) void iwt_kernel(
    const float* __restrict__ x,
    const float* __restrict__ filt,
    float* __restrict__ out)
{
    constexpr int H = 128, W = 128;
    constexpr int HW = H * W;           // 16384
    constexpr int OPLANE = (2 * H) * (2 * W); // 65536
    constexpr int OW = 2 * W;           // 256

    int tid = blockIdx.x * blockDim.x + threadIdx.x; // 0 .. 8388607
    int tw = tid & 63;            // w-pair index, W2=64
    int h  = (tid >> 6) & 127;    // H=128
    int bg = tid >> 13;           // b*G + g, 0..1023

    // channel plane index of x0 = b*C + 2g = 2*bg
    int x0off = (2 * bg) * HW + h * W + 2 * tw;

    const float2 x0 = *(const float2*)(x + x0off);
    const float2 x1 = *(const float2*)(x + x0off + HW);

    // filters: f0[i][j] = filt[i*2+j], f1[i][j] = filt[4+i*2+j]
    // uniform address -> scalar loads, hoisted
    float f000 = filt[0], f001 = filt[1], f010 = filt[2], f011 = filt[3];
    float f100 = filt[4], f101 = filt[5], f110 = filt[6], f111 = filt[7];

    float4 r0, r1;
    r0.x = x0.x * f000 + x1.x * f100;
    r0.y = x0.x * f001 + x1.x * f101;
    r0.z = x0.y * f000 + x1.y * f100;
    r0.w = x0.y * f001 + x1.y * f101;

    r1.x = x0.x * f010 + x1.x * f110;
    r1.y = x0.x * f011 + x1.x * f111;
    r1.z = x0.y * f010 + x1.y * f110;
    r1.w = x0.y * f011 + x1.y * f111;

    int ooff = bg * OPLANE + (2 * h) * OW + 4 * tw;
    *(float4*)(out + ooff)      = r0;
    *(float4*)(out + ooff + OW) = r1;
}

extern "C" void kernel_launch(void* const* d_in, const int* in_sizes, int n_in,
                              void* d_out, int out_size, void* d_ws, size_t ws_size,
                              hipStream_t stream) {
    const float* x    = (const float*)d_in[0];
    const float* filt = (const float*)d_in[1];
    float* out        = (float*)d_out;

    // total threads = 16*64*128*64 = 8388608
    constexpr int total = 16 * 64 * 128 * 64;
    constexpr int block = 256;
    iwt_kernel<<<total / block, block, 0, stream>>>(x, filt, out);
}

// Round 2
// 342.998 us; speedup vs baseline: 1.0041x; 1.0041x over previous
//
#include <hip/hip_runtime.h>

// db1 inverse wavelet transform (grouped transposed conv, k=2, stride=2).
// x: (B=16, C=128, H=128, W=128) fp32 -> out: (B=16, G=64, 256, 256) fp32.
// out[b,g,2h+i,2w+j] = x[b,2g,h,w]*f0[i][j] + x[b,2g+1,h,w]*f1[i][j]
//
// Memory-bound streaming op: 128 MiB read + 256 MiB write -> ~63 us at the
// fill-measured 6.4 TB/s. R1: nontemporal loads/stores — data is touched
// exactly once, so bypass cache allocation (output is 256 MiB = entire L3).

typedef float v2f __attribute__((ext_vector_type(2)));
typedef float v4f __attribute__((ext_vector_type(4)));

__global__ __launch_bounds__(256) void iwt_kernel(
    const float* __restrict__ x,
    const float* __restrict__ filt,
    float* __restrict__ out)
{
    constexpr int H = 128, W = 128;
    constexpr int HW = H * W;                 // 16384
    constexpr int OPLANE = (2 * H) * (2 * W); // 65536
    constexpr int OW = 2 * W;                 // 256

    int tid = blockIdx.x * blockDim.x + threadIdx.x; // 0 .. 8388607
    int tw = tid & 63;            // w-pair index, W2=64
    int h  = (tid >> 6) & 127;    // H=128
    int bg = tid >> 13;           // b*G + g, 0..1023

    // channel plane index of x0 = b*C + 2g = 2*bg
    int x0off = (2 * bg) * HW + h * W + 2 * tw;

    const v2f x0 = __builtin_nontemporal_load((const v2f*)(x + x0off));
    const v2f x1 = __builtin_nontemporal_load((const v2f*)(x + x0off + HW));

    // filters: f0[i][j] = filt[i*2+j], f1[i][j] = filt[4+i*2+j]
    // uniform address -> scalar loads, hoisted
    float f000 = filt[0], f001 = filt[1], f010 = filt[2], f011 = filt[3];
    float f100 = filt[4], f101 = filt[5], f110 = filt[6], f111 = filt[7];

    v4f r0, r1;
    r0.x = x0.x * f000 + x1.x * f100;
    r0.y = x0.x * f001 + x1.x * f101;
    r0.z = x0.y * f000 + x1.y * f100;
    r0.w = x0.y * f001 + x1.y * f101;

    r1.x = x0.x * f010 + x1.x * f110;
    r1.y = x0.x * f011 + x1.x * f111;
    r1.z = x0.y * f010 + x1.y * f110;
    r1.w = x0.y * f011 + x1.y * f111;

    int ooff = bg * OPLANE + (2 * h) * OW + 4 * tw;
    __builtin_nontemporal_store(r0, (v4f*)(out + ooff));
    __builtin_nontemporal_store(r1, (v4f*)(out + ooff + OW));
}

extern "C" void kernel_launch(void* const* d_in, const int* in_sizes, int n_in,
                              void* d_out, int out_size, void* d_ws, size_t ws_size,
                              hipStream_t stream) {
    const float* x    = (const float*)d_in[0];
    const float* filt = (const float*)d_in[1];
    float* out        = (float*)d_out;

    // total threads = 16*64*128*64 = 8388608
    constexpr int total = 16 * 64 * 128 * 64;
    constexpr int block = 256;
    iwt_kernel<<<total / block, block, 0, stream>>>(x, filt, out);
}